// Round 17
// baseline (320.256 us; speedup 1.0000x reference)
//
#include <hip/hip_runtime.h>
#include <math.h>

#define NN 10000
#define EE 320000
#define INC 64
#define HH 128
#define G4 512
#define SEG 250
#define QLEN (NN / SEG)
#define WARM 24

typedef short short8 __attribute__((ext_vector_type(8)));
typedef short short4v __attribute__((ext_vector_type(4)));
typedef float f32x4 __attribute__((ext_vector_type(4)));

__device__ __forceinline__ float sigm(float x) { return 1.f / (1.f + __expf(-x)); }
__device__ __forceinline__ float tanh_fast(float x) { return 1.f - 2.f / (1.f + __expf(2.f * x)); }

// fp32 -> bf16 round-to-nearest-even
__device__ __forceinline__ unsigned short f2bf(float f) {
    unsigned u = __float_as_uint(f);
    unsigned r = u + 0x7FFFu + ((u >> 16) & 1u);
    return (unsigned short)(r >> 16);
}
__device__ __forceinline__ float bf2f(unsigned short b) {
    return __uint_as_float(((unsigned)b) << 16);
}
__device__ __forceinline__ f32x4 bf4_to_f32(short4v v) {
    f32x4 r;
    r[0] = bf2f((unsigned short)v[0]);
    r[1] = bf2f((unsigned short)v[1]);
    r[2] = bf2f((unsigned short)v[2]);
    r[3] = bf2f((unsigned short)v[3]);
    return r;
}

// ---------------- zero stats + edge counters ----------------
__global__ void k_zero(float* stats, int* cnt) {
    int i = blockIdx.x * 256 + threadIdx.x;
    if (i < 512) stats[i] = 0.f;
    if (i < NN) cnt[i] = 0;
}

// ---- histogram of dst + Wih->bf16 + bias sums + W1/W2 transposed bf16 fragments ----
__global__ void k_hist(const int* __restrict__ ei, int* __restrict__ cnt,
                       const float* __restrict__ Wf, const float* __restrict__ Wb,
                       const float* __restrict__ bif, const float* __restrict__ bhf,
                       const float* __restrict__ bib, const float* __restrict__ bhb,
                       const float* __restrict__ W1, const float* __restrict__ W2,
                       unsigned short* __restrict__ wf, unsigned short* __restrict__ wb,
                       unsigned short* __restrict__ w1t, unsigned short* __restrict__ w2t,
                       float* __restrict__ bsf, float* __restrict__ bsb) {
    int i = blockIdx.x * 256 + threadIdx.x;
    if (i < EE) atomicAdd(&cnt[ei[EE + i]], 1);
    if (i < 512) bsf[i] = bif[i] + bhf[i];
    else if (i < 1024) bsb[i - 512] = bib[i - 512] + bhb[i - 512];
    else if (i < 1024 + 65536) wf[i - 1024] = f2bf(Wf[i - 1024]);
    else if (i < 1024 + 131072) wb[i - 1024 - 65536] = f2bf(Wb[i - 1024 - 65536]);
    else if (i < 132096 + 8192) {                 // W1[64][128] -> w1t[128][64]
        int j = i - 132096;
        int n = j >> 6, k = j & 63;
        w1t[j] = f2bf(W1[k * 128 + n]);
    } else if (i < 140288 + 16384) {              // W2[128][128] -> w2t[128][128]
        int j = i - 140288;
        int n = j >> 7, k = j & 127;
        w2t[j] = f2bf(W2[k * 128 + n]);
    }
}

// ---------------- exclusive scan of cnt -> off; re-zero cnt ----------------
__global__ __launch_bounds__(1024) void k_scan(int* __restrict__ cnt, int* __restrict__ off) {
    __shared__ int part[1024];
    int i = threadIdx.x;
    int base = i * 10;
    int s = 0;
#pragma unroll
    for (int k = 0; k < 10; ++k) { int idx = base + k; if (idx < NN) s += cnt[idx]; }
    part[i] = s;
    __syncthreads();
    for (int d = 1; d < 1024; d <<= 1) {   // Hillis-Steele inclusive scan
        int v = (i >= d) ? part[i - d] : 0;
        __syncthreads();
        part[i] += v;
        __syncthreads();
    }
    int run = (i > 0) ? part[i - 1] : 0;
#pragma unroll
    for (int k = 0; k < 10; ++k) {
        int idx = base + k;
        if (idx < NN) { off[idx] = run; run += cnt[idx]; cnt[idx] = 0; }
    }
    if (i == 1023) off[NN] = part[1023];
}

// ---------------- fill CSR: packed {src, w_bits} pairs in dst order ----------------
__global__ void k_fill(const int* __restrict__ ei, const float* __restrict__ ew,
                       const int* __restrict__ off, int* __restrict__ cnt,
                       int2* __restrict__ csw) {
    int e = blockIdx.x * 256 + threadIdx.x;
    if (e >= EE) return;
    int dst = ei[EE + e];
    int pos = off[dst] + atomicAdd(&cnt[dst], 1);
    csw[pos] = make_int2(ei[e], __float_as_int(ew[e]));
}

// ---------------- C_bf16[M,128] = BNReLU?(A)[M,K] @ W, bf16 MFMA ----------------
__global__ __launch_bounds__(256) void k_gemm_mfma(const float* __restrict__ A,
                                                    const unsigned short* __restrict__ Wt,
                                                    unsigned short* __restrict__ C,
                                                    const float* __restrict__ bnst,
                                                    const float* __restrict__ bng,
                                                    const float* __restrict__ bnbe,
                                                    int KT) {
    const int K = KT * 32;
    __shared__ __align__(16) unsigned short Asub[64 * 128];
    __shared__ float albe[256];
    int tid = threadIdx.x;
    int m0 = blockIdx.x * 64;
    if (bnst) {
        if (tid < 128) {
            float mean = bnst[tid] * (1.f / NN);
            float var = fmaf(-mean, mean, bnst[128 + tid] * (1.f / NN));
            float alpha = bng[tid] * rsqrtf(var + 1e-5f);
            albe[tid] = alpha;
            albe[128 + tid] = fmaf(-mean, alpha, bnbe[tid]);
        }
        __syncthreads();
    }
    const int kg8 = K >> 3;                       // 8-elem groups per row
    for (int i = tid; i < 64 * kg8; i += 256) {
        int r = i / kg8, kg = i - r * kg8;
        int m = m0 + r;
        short8 v8 = (short8){0, 0, 0, 0, 0, 0, 0, 0};
        if (m < NN) {
            f32x4 a0 = *(const f32x4*)(A + m * K + kg * 8);
            f32x4 a1 = *(const f32x4*)(A + m * K + kg * 8 + 4);
            if (bnst) {
#pragma unroll
                for (int e = 0; e < 4; ++e) {
                    int c = kg * 8 + e;
                    v8[e] = (short)f2bf(fmaxf(0.f, fmaf(a0[e], albe[c], albe[128 + c])));
                }
#pragma unroll
                for (int e = 0; e < 4; ++e) {
                    int c = kg * 8 + 4 + e;
                    v8[4 + e] = (short)f2bf(fmaxf(0.f, fmaf(a1[e], albe[c], albe[128 + c])));
                }
            } else {
#pragma unroll
                for (int e = 0; e < 4; ++e) v8[e] = (short)f2bf(a0[e]);
#pragma unroll
                for (int e = 0; e < 4; ++e) v8[4 + e] = (short)f2bf(a1[e]);
            }
        }
        *(short8*)(&Asub[r * K + kg * 8]) = v8;
    }
    __syncthreads();

    int lane = tid & 63, wv = tid >> 6;
    int q = lane >> 4, n = lane & 15;
    short8 afr[4];
#pragma unroll
    for (int kt = 0; kt < 4; ++kt)
        if (kt < KT) afr[kt] = *(const short8*)(&Asub[(16 * wv + n) * K + kt * 32 + q * 8]);

    for (int nt = 0; nt < 8; ++nt) {
        int wrow = nt * 16 + n;
        f32x4 acc = (f32x4){0.f, 0.f, 0.f, 0.f};
#pragma unroll
        for (int kt = 0; kt < 4; ++kt) {
            if (kt < KT) {
                short8 bfr = *(const short8*)(Wt + wrow * K + kt * 32 + q * 8);
                acc = __builtin_amdgcn_mfma_f32_16x16x32_bf16(afr[kt], bfr, acc, 0, 0, 0);
            }
        }
#pragma unroll
        for (int r = 0; r < 4; ++r) {
            int m = m0 + 16 * wv + 4 * q + r;
            if (m < NN) C[m * 128 + wrow] = f2bf(acc[r]);
        }
    }
}

// ---------------- CSR gather over bf16 h, 8 edge-groups per node, no atomics ----------------
__global__ __launch_bounds__(256) void k_gather(const unsigned short* __restrict__ h,
                                                 const int2* __restrict__ csw,
                                                 const int* __restrict__ off,
                                                 const float* __restrict__ bias,
                                                 float* __restrict__ agg) {
    int tid = threadIdx.x;
    int node = blockIdx.x;
    int g = tid >> 5;                  // edge group 0..7
    int q32 = tid & 31;
    f32x4 acc = (f32x4){0.f, 0.f, 0.f, 0.f};
    int beg = off[node], end = off[node + 1];

    int i = beg + g;
    int2 sw = (i < end) ? csw[i] : make_int2(0, 0);   // w=0 -> no-op contribution
    while (i < end) {
        int inext = i + 8;
        int2 swn = (inext < end) ? csw[inext] : make_int2(0, 0);
        float w = __int_as_float(sw.y);
        short4v hv = *(const short4v*)(h + sw.x * 128 + q32 * 4);
        f32x4 v = bf4_to_f32(hv);
        acc[0] = fmaf(v[0], w, acc[0]);
        acc[1] = fmaf(v[1], w, acc[1]);
        acc[2] = fmaf(v[2], w, acc[2]);
        acc[3] = fmaf(v[3], w, acc[3]);
        sw = swn;
        i = inext;
    }

    // combine the 8 groups
    __shared__ f32x4 part[256];
    part[tid] = acc;
    __syncthreads();
    if (g == 0) {
        f32x4 s = part[q32];
#pragma unroll
        for (int gg = 1; gg < 8; ++gg) s += part[gg * 32 + q32];
        const f32x4 bv = *(const f32x4*)(bias + q32 * 4);
        s += bv;
        *(f32x4*)(agg + node * 128 + q32 * 4) = s;
    }
}

// ---------------- per-feature sum / sumsq ----------------
__global__ __launch_bounds__(256) void k_bn_stats(const float* __restrict__ x,
                                                   float* __restrict__ stats) {
    int c = threadIdx.x & 127;
    int half = threadIdx.x >> 7;
    float s = 0.f, q = 0.f;
    for (int r = blockIdx.x * 2 + half; r < NN; r += gridDim.x * 2) {
        float v = x[r * HH + c];
        s += v;
        q = fmaf(v, v, q);
    }
    __shared__ float ls[256], lq[256];
    ls[threadIdx.x] = s;
    lq[threadIdx.x] = q;
    __syncthreads();
    if (half == 0) {
        atomicAdd(&stats[c], s + ls[128 + c]);
        atomicAdd(&stats[128 + c], q + lq[128 + c]);
    }
}

// ---------------- X_bf16[m][f][gate] = bf16(BNReLU(agg))[m,k] @ W_bf[gr,k]^T + bsum ----------------
__global__ __launch_bounds__(256) void k_mm512p(const float* __restrict__ A,
                                                 const float* __restrict__ bnst,
                                                 const float* __restrict__ bng,
                                                 const float* __restrict__ bnbe,
                                                 const unsigned short* __restrict__ Wfp,
                                                 const unsigned short* __restrict__ Wbp,
                                                 const float* __restrict__ bsf,
                                                 const float* __restrict__ bsb,
                                                 unsigned short* __restrict__ Xf,
                                                 unsigned short* __restrict__ Xb) {
    const int dir = blockIdx.y;
    const unsigned short* __restrict__ W = dir ? Wbp : Wfp;
    const float* __restrict__ bs = dir ? bsb : bsf;
    unsigned short* __restrict__ X = dir ? Xb : Xf;

    __shared__ __align__(16) unsigned short Asub[64 * 128];   // 16 KB
    __shared__ float albe[256];
    int tid = threadIdx.x;
    int m0 = blockIdx.x * 64;
    if (tid < 128) {
        float mean = bnst[tid] * (1.f / NN);
        float var = fmaf(-mean, mean, bnst[128 + tid] * (1.f / NN));
        float alpha = bng[tid] * rsqrtf(var + 1e-5f);
        albe[tid] = alpha;
        albe[128 + tid] = fmaf(-mean, alpha, bnbe[tid]);
    }
    __syncthreads();
    for (int i = tid; i < 1024; i += 256) {     // 64 rows x 16 (8-elem groups)
        int r = i >> 4, kg = i & 15;
        int m = m0 + r;
        short8 v8 = (short8){0, 0, 0, 0, 0, 0, 0, 0};
        if (m < NN) {
            f32x4 a0 = *(const f32x4*)(A + m * 128 + kg * 8);
            f32x4 a1 = *(const f32x4*)(A + m * 128 + kg * 8 + 4);
#pragma unroll
            for (int e = 0; e < 4; ++e) {
                int c = kg * 8 + e;
                v8[e] = (short)f2bf(fmaxf(0.f, fmaf(a0[e], albe[c], albe[128 + c])));
            }
#pragma unroll
            for (int e = 0; e < 4; ++e) {
                int c = kg * 8 + 4 + e;
                v8[4 + e] = (short)f2bf(fmaxf(0.f, fmaf(a1[e], albe[c], albe[128 + c])));
            }
        }
        *(short8*)(&Asub[r * 128 + kg * 8]) = v8;
    }
    __syncthreads();

    int lane = tid & 63, wv = tid >> 6;
    int q = lane >> 4, n = lane & 15;
    short8 afr[4];
#pragma unroll
    for (int kt = 0; kt < 4; ++kt)
        afr[kt] = *(const short8*)(&Asub[(16 * wv + n) * 128 + kt * 32 + q * 8]);

    for (int nt = 0; nt < 32; ++nt) {
        int gr = nt * 16 + n;
        short8 bfr[4];
#pragma unroll
        for (int kt = 0; kt < 4; ++kt)
            bfr[kt] = *(const short8*)(W + gr * 128 + kt * 32 + q * 8);
        f32x4 acc = (f32x4){0.f, 0.f, 0.f, 0.f};
#pragma unroll
        for (int kt = 0; kt < 4; ++kt)
            acc = __builtin_amdgcn_mfma_f32_16x16x32_bf16(afr[kt], bfr[kt], acc, 0, 0, 0);
        float b = bs[gr];
        int fg4 = (gr & 127) * 4 + (gr >> 7);
#pragma unroll
        for (int r = 0; r < 4; ++r) {
            int m = m0 + 16 * wv + 4 * q + r;
            if (m < NN) X[m * 512 + fg4] = f2bf(acc[r] + b);
        }
    }
}

// ---------------- segmented bidirectional LSTM scan (WARM=24, SEG=250, bf16 X) ----------------
// R17: 500 blocks ~ 2/CU. Unlike R7 (16 barrier-locked waves in ONE block),
// two independent 8-wave blocks interleave freely on the SIMDs -> latency
// chains overlap. Steps/block 104 -> 64.
__global__ __launch_bounds__(512, 1) void k_lstm(const unsigned short* __restrict__ xpf,
                                                  const unsigned short* __restrict__ xpb,
                                                  const float* __restrict__ whf,
                                                  const float* __restrict__ whb,
                                                  float* __restrict__ hf,
                                                  float* __restrict__ hb) {
    const int seg = blockIdx.x;
    const int dir = blockIdx.y;
    const unsigned short* __restrict__ xp = dir ? xpb : xpf;
    const float* __restrict__ Whh = dir ? whb : whf;
    float* __restrict__ hsp = dir ? hb : hf;
    const int j = threadIdx.x;
    const int lane = j & 63;
    const int w = j >> 6;
    const int g16 = lane >> 4;
    const int m = lane & 15;
    const int r2 = m & 3;
    const int f1 = 16 * w + 4 * g16 + r2;
    const bool writer = (m < 4);

    short8 af[4][4];
#pragma unroll
    for (int gt = 0; gt < 4; ++gt) {
#pragma unroll
        for (int kt = 0; kt < 4; ++kt) {
            const float* wp = Whh + (128 * gt + 16 * w + m) * 128 + 32 * kt + 8 * g16;
            float4 q0 = *(const float4*)wp;
            float4 q1 = *(const float4*)(wp + 4);
            short8 a;
            a[0] = (short)f2bf(q0.x); a[1] = (short)f2bf(q0.y);
            a[2] = (short)f2bf(q0.z); a[3] = (short)f2bf(q0.w);
            a[4] = (short)f2bf(q1.x); a[5] = (short)f2bf(q1.y);
            a[6] = (short)f2bf(q1.z); a[7] = (short)f2bf(q1.w);
            af[gt][kt] = a;
        }
    }

    __shared__ __align__(16) short h_bf[2][128];
    if (j < 128) h_bf[0][j] = 0;
    float c = 0.f;
    __syncthreads();

    // segment geometry (warm in {0,24}, QLEN=40: all even => loops stay 2x-unrolled)
    int warm, tfirst, tout;
    if (dir == 0) {
        int pre = seg * QLEN;
        warm = (pre < WARM) ? pre : WARM;
        tfirst = pre - warm;
        tout = pre;
    } else {
        int post = NN - (seg + 1) * QLEN;
        warm = (post < WARM) ? post : WARM;
        tfirst = (seg + 1) * QLEN - 1 + warm;
        tout = (seg + 1) * QLEN - 1;
    }

    const int xinc = dir ? -G4 : G4;               // ushorts per step
    const int hinc = dir ? -HH : HH;
    const unsigned short* xptr = xp + (size_t)tfirst * G4 + f1 * 4;
    float* hptr = hsp + tout * HH + f1;

    f32x4 xE = bf4_to_f32(*(const short4v*)xptr); xptr += xinc;
    f32x4 xO = bf4_to_f32(*(const short4v*)xptr); xptr += xinc;

#define LSTM_STEP(BUFR, BUFW, XV, WR)                                                    \
    {                                                                                    \
        const short8* hb8 = (const short8*)h_bf[BUFR];                                   \
        short8 bf0 = hb8[g16], bf1 = hb8[4 + g16], bf2 = hb8[8 + g16], bf3 = hb8[12 + g16]; \
        f32x4 acc[4];                                                                    \
        _Pragma("unroll")                                                                \
        for (int gt = 0; gt < 4; ++gt) acc[gt] = (f32x4){0.f, 0.f, 0.f, 0.f};            \
        _Pragma("unroll")                                                                \
        for (int gt = 0; gt < 4; ++gt)                                                   \
            acc[gt] = __builtin_amdgcn_mfma_f32_16x16x32_bf16(af[gt][0], bf0, acc[gt], 0, 0, 0); \
        _Pragma("unroll")                                                                \
        for (int gt = 0; gt < 4; ++gt)                                                   \
            acc[gt] = __builtin_amdgcn_mfma_f32_16x16x32_bf16(af[gt][1], bf1, acc[gt], 0, 0, 0); \
        _Pragma("unroll")                                                                \
        for (int gt = 0; gt < 4; ++gt)                                                   \
            acc[gt] = __builtin_amdgcn_mfma_f32_16x16x32_bf16(af[gt][2], bf2, acc[gt], 0, 0, 0); \
        _Pragma("unroll")                                                                \
        for (int gt = 0; gt < 4; ++gt)                                                   \
            acc[gt] = __builtin_amdgcn_mfma_f32_16x16x32_bf16(af[gt][3], bf3, acc[gt], 0, 0, 0); \
        float gv[4];                                                                     \
        _Pragma("unroll")                                                                \
        for (int r = 0; r < 4; ++r) {                                                    \
            float lo = (r2 & 1) ? acc[r][1] : acc[r][0];                                 \
            float hi = (r2 & 1) ? acc[r][3] : acc[r][2];                                 \
            gv[r] = (r2 & 2) ? hi : lo;                                                  \
        }                                                                                \
        float ig = sigm(gv[0] + (XV)[0]);                                                \
        float fg = sigm(gv[1] + (XV)[1]);                                                \
        float cg = tanh_fast(gv[2] + (XV)[2]);                                           \
        float og = sigm(gv[3] + (XV)[3]);                                                \
        c = fmaf(fg, c, ig * cg);                                                        \
        float h = og * tanh_fast(c);                                                     \
        if (writer) {                                                                    \
            if (WR) *hptr = h;                                                           \
            h_bf[BUFW][f1] = (short)f2bf(h);                                             \
        }                                                                                \
        if (WR) hptr += hinc;                                                            \
    }

    // ---- warmup (no output writes) ----
    for (int s = 0; s < warm; s += 2) {
        f32x4 xE2 = bf4_to_f32(*(const short4v*)xptr); xptr += xinc;
        LSTM_STEP(0, 1, xE, 0)
        asm volatile("s_waitcnt lgkmcnt(0)\n\ts_barrier" ::: "memory");

        f32x4 xO2 = bf4_to_f32(*(const short4v*)xptr); xptr += xinc;
        LSTM_STEP(1, 0, xO, 0)
        asm volatile("s_waitcnt lgkmcnt(0)\n\ts_barrier" ::: "memory");

        xE = xE2;
        xO = xO2;
    }
    // ---- main (writes enabled) ----
    for (int s = 0; s < QLEN; s += 2) {
        f32x4 xE2 = bf4_to_f32(*(const short4v*)xptr); xptr += xinc;
        LSTM_STEP(0, 1, xE, 1)
        asm volatile("s_waitcnt lgkmcnt(0)\n\ts_barrier" ::: "memory");

        f32x4 xO2 = bf4_to_f32(*(const short4v*)xptr); xptr += xinc;
        LSTM_STEP(1, 0, xO, 1)
        asm volatile("s_waitcnt lgkmcnt(0)\n\ts_barrier" ::: "memory");

        xE = xE2;
        xO = xO2;
    }
#undef LSTM_STEP
}

// ---------------- out = [hf|hb] @ Wo + bo ----------------
__global__ void k_out(const float* __restrict__ hf, const float* __restrict__ hb,
                      const float* __restrict__ Wo, const float* __restrict__ bo,
                      float* __restrict__ out) {
    int idx = blockIdx.x * 256 + threadIdx.x;
    if (idx >= NN * 12) return;
    int n = idx / 12;
    int p = idx - n * 12;
    float acc = bo[p];
    const float4* hfr = (const float4*)(hf + n * 128);
    const float4* hbr = (const float4*)(hb + n * 128);
#pragma unroll 4
    for (int k4 = 0; k4 < 32; ++k4) {
        float4 v = hfr[k4];
        acc = fmaf(v.x, Wo[(4 * k4 + 0) * 12 + p], acc);
        acc = fmaf(v.y, Wo[(4 * k4 + 1) * 12 + p], acc);
        acc = fmaf(v.z, Wo[(4 * k4 + 2) * 12 + p], acc);
        acc = fmaf(v.w, Wo[(4 * k4 + 3) * 12 + p], acc);
    }
#pragma unroll 4
    for (int k4 = 0; k4 < 32; ++k4) {
        float4 v = hbr[k4];
        acc = fmaf(v.x, Wo[(128 + 4 * k4 + 0) * 12 + p], acc);
        acc = fmaf(v.y, Wo[(128 + 4 * k4 + 1) * 12 + p], acc);
        acc = fmaf(v.z, Wo[(128 + 4 * k4 + 2) * 12 + p], acc);
        acc = fmaf(v.w, Wo[(128 + 4 * k4 + 3) * 12 + p], acc);
    }
    out[idx] = acc;
}

extern "C" void kernel_launch(void* const* d_in, const int* in_sizes, int n_in,
                              void* d_out, int out_size, void* d_ws, size_t ws_size,
                              hipStream_t stream) {
    const float* x    = (const float*)d_in[0];
    const int*   ei   = (const int*)d_in[1];
    const float* ew   = (const float*)d_in[2];
    const float* W1   = (const float*)d_in[3];
    const float* b1   = (const float*)d_in[4];
    const float* g1   = (const float*)d_in[5];
    const float* be1  = (const float*)d_in[6];
    const float* W2   = (const float*)d_in[7];
    const float* b2   = (const float*)d_in[8];
    const float* g2   = (const float*)d_in[9];
    const float* be2  = (const float*)d_in[10];
    const float* Wihf = (const float*)d_in[11];
    const float* Whhf = (const float*)d_in[12];
    const float* bihf = (const float*)d_in[13];
    const float* bhhf = (const float*)d_in[14];
    const float* Wihb = (const float*)d_in[15];
    const float* Whhb = (const float*)d_in[16];
    const float* bihb = (const float*)d_in[17];
    const float* bhhb = (const float*)d_in[18];
    const float* Wo   = (const float*)d_in[21];
    const float* bo   = (const float*)d_in[22];
    float* out = (float*)d_out;
    float* ws  = (float*)d_ws;

    // ---- buffers (float offsets; bf16 buffers reinterpret the same regions) ----
    unsigned short* bufA = (unsigned short*)ws;        // 1.28M ushort (GEMM out, bf16)
    float* bufB  = ws + 1280000;       // 1,280,000 fp32 (agg)
    float* stats = ws + 3840000;       // 512
    unsigned short* Xf = (unsigned short*)(ws + 3840512);   // 5.12M ushort
    unsigned short* Xb = (unsigned short*)(ws + 8960512);   // 5.12M ushort
    float* hfp   = ws + 14080512;      // 1,280,000
    float* hbp   = ws + 15360512;      // 1,280,000

    // ---- overlay region inside hfp/hbp (all consumed before k_lstm writes them) ----
    // Disjointness audit (float offsets):
    //   wfbf [14,720,512 - 14,753,280)  wbbf [14,753,280 - 14,786,048)
    //   bsumf[14,786,048 - 14,786,560)  bsumb[14,786,560 - 14,787,072)
    //   icnt [14,787,072 - 14,797,072)  ioff [14,797,072 - 14,807,073)
    //   csw  [14,807,074 - 15,447,074)
    //   w1t  [15,447,076 - 15,451,172)  w2t [15,451,172 - 15,459,364)
    unsigned short* wfbf = (unsigned short*)(ws + 14720512);
    unsigned short* wbbf = (unsigned short*)(ws + 14753280);
    float* bsumf = ws + 14786048;
    float* bsumb = ws + 14786560;
    int* icnt = (int*)(ws + 14787072);
    int* ioff = icnt + 10000;
    int2* csw = (int2*)(ws + 14807074);
    unsigned short* w1t  = (unsigned short*)(ws + 15447076);
    unsigned short* w2t  = (unsigned short*)(ws + 15451172);

    const int gEdge = (EE + 255) / 256;

    // ---- CSR build + weight converts ----
    k_zero<<<(NN + 255) / 256, 256, 0, stream>>>(stats, icnt);
    k_hist<<<gEdge, 256, 0, stream>>>(ei, icnt, Wihf, Wihb, bihf, bhhf, bihb, bhhb,
                                      W1, W2, wfbf, wbbf, w1t, w2t, bsumf, bsumb);
    k_scan<<<1, 1024, 0, stream>>>(icnt, ioff);
    k_fill<<<gEdge, 256, 0, stream>>>(ei, ew, ioff, icnt, csw);

    // ---- GCN layer 1 (bf16 MFMA, bf16 out) ----
    k_gemm_mfma<<<157, 256, 0, stream>>>(x, w1t, bufA,
                                         (const float*)0, (const float*)0, (const float*)0, 2);
    k_gather<<<NN, 256, 0, stream>>>(bufA, csw, ioff, b1, bufB);
    k_bn_stats<<<100, 256, 0, stream>>>(bufB, stats);

    // ---- GCN layer 2 (BN1+ReLU fused into bf16 staging, MFMA, bf16 out) ----
    k_gemm_mfma<<<157, 256, 0, stream>>>(bufB, w2t, bufA, stats, g1, be1, 4);
    k_gather<<<NN, 256, 0, stream>>>(bufA, csw, ioff, b2, bufB);
    k_bn_stats<<<100, 256, 0, stream>>>(bufB, stats + 256);

    // ---- LSTM input projections (BN2+ReLU+bf16 fused; X stored bf16) ----
    dim3 gmm(157, 2);
    k_mm512p<<<gmm, 256, 0, stream>>>(bufB, stats + 256, g2, be2,
                                      wfbf, wbbf, bsumf, bsumb, Xf, Xb);

    // ---- segmented bidirectional scan: SEG x 2 dirs, 64 steps max ----
    dim3 gl(SEG, 2);
    k_lstm<<<gl, 512, 0, stream>>>(Xf, Xb, Whhf, Whhb, hfp, hbp);

    // ---- attention is identity; final matmul ----
    k_out<<<(NN * 12 + 255) / 256, 256, 0, stream>>>(hfp, hbp, Wo, bo, out);
}

// Round 18
// 291.518 us; speedup vs baseline: 1.0986x; 1.0986x over previous
//
#include <hip/hip_runtime.h>
#include <math.h>

#define NN 10000
#define EE 320000
#define INC 64
#define HH 128
#define G4 512
#define SEG 125
#define QLEN (NN / SEG)
#define WARM 24

typedef short short8 __attribute__((ext_vector_type(8)));
typedef short short4v __attribute__((ext_vector_type(4)));
typedef float f32x4 __attribute__((ext_vector_type(4)));

__device__ __forceinline__ float sigm(float x) { return 1.f / (1.f + __expf(-x)); }
__device__ __forceinline__ float tanh_fast(float x) { return 1.f - 2.f / (1.f + __expf(2.f * x)); }

// fp32 -> bf16 round-to-nearest-even
__device__ __forceinline__ unsigned short f2bf(float f) {
    unsigned u = __float_as_uint(f);
    unsigned r = u + 0x7FFFu + ((u >> 16) & 1u);
    return (unsigned short)(r >> 16);
}
__device__ __forceinline__ float bf2f(unsigned short b) {
    return __uint_as_float(((unsigned)b) << 16);
}
__device__ __forceinline__ f32x4 bf4_to_f32(short4v v) {
    f32x4 r;
    r[0] = bf2f((unsigned short)v[0]);
    r[1] = bf2f((unsigned short)v[1]);
    r[2] = bf2f((unsigned short)v[2]);
    r[3] = bf2f((unsigned short)v[3]);
    return r;
}

// ---------------- zero stats + edge counters ----------------
__global__ void k_zero(float* stats, int* cnt) {
    int i = blockIdx.x * 256 + threadIdx.x;
    if (i < 512) stats[i] = 0.f;
    if (i < NN) cnt[i] = 0;
}

// ---- histogram of dst + Wih->bf16 + bias sums + W1/W2 transposed bf16 fragments ----
__global__ void k_hist(const int* __restrict__ ei, int* __restrict__ cnt,
                       const float* __restrict__ Wf, const float* __restrict__ Wb,
                       const float* __restrict__ bif, const float* __restrict__ bhf,
                       const float* __restrict__ bib, const float* __restrict__ bhb,
                       const float* __restrict__ W1, const float* __restrict__ W2,
                       unsigned short* __restrict__ wf, unsigned short* __restrict__ wb,
                       unsigned short* __restrict__ w1t, unsigned short* __restrict__ w2t,
                       float* __restrict__ bsf, float* __restrict__ bsb) {
    int i = blockIdx.x * 256 + threadIdx.x;
    if (i < EE) atomicAdd(&cnt[ei[EE + i]], 1);
    if (i < 512) bsf[i] = bif[i] + bhf[i];
    else if (i < 1024) bsb[i - 512] = bib[i - 512] + bhb[i - 512];
    else if (i < 1024 + 65536) wf[i - 1024] = f2bf(Wf[i - 1024]);
    else if (i < 1024 + 131072) wb[i - 1024 - 65536] = f2bf(Wb[i - 1024 - 65536]);
    else if (i < 132096 + 8192) {                 // W1[64][128] -> w1t[128][64]
        int j = i - 132096;
        int n = j >> 6, k = j & 63;
        w1t[j] = f2bf(W1[k * 128 + n]);
    } else if (i < 140288 + 16384) {              // W2[128][128] -> w2t[128][128]
        int j = i - 140288;
        int n = j >> 7, k = j & 127;
        w2t[j] = f2bf(W2[k * 128 + n]);
    }
}

// ---------------- exclusive scan of cnt -> off; re-zero cnt ----------------
__global__ __launch_bounds__(1024) void k_scan(int* __restrict__ cnt, int* __restrict__ off) {
    __shared__ int part[1024];
    int i = threadIdx.x;
    int base = i * 10;
    int s = 0;
#pragma unroll
    for (int k = 0; k < 10; ++k) { int idx = base + k; if (idx < NN) s += cnt[idx]; }
    part[i] = s;
    __syncthreads();
    for (int d = 1; d < 1024; d <<= 1) {   // Hillis-Steele inclusive scan
        int v = (i >= d) ? part[i - d] : 0;
        __syncthreads();
        part[i] += v;
        __syncthreads();
    }
    int run = (i > 0) ? part[i - 1] : 0;
#pragma unroll
    for (int k = 0; k < 10; ++k) {
        int idx = base + k;
        if (idx < NN) { off[idx] = run; run += cnt[idx]; cnt[idx] = 0; }
    }
    if (i == 1023) off[NN] = part[1023];
}

// ---------------- fill CSR: packed {src, w_bits} pairs in dst order ----------------
__global__ void k_fill(const int* __restrict__ ei, const float* __restrict__ ew,
                       const int* __restrict__ off, int* __restrict__ cnt,
                       int2* __restrict__ csw) {
    int e = blockIdx.x * 256 + threadIdx.x;
    if (e >= EE) return;
    int dst = ei[EE + e];
    int pos = off[dst] + atomicAdd(&cnt[dst], 1);
    csw[pos] = make_int2(ei[e], __float_as_int(ew[e]));
}

// ---------------- C_bf16[M,128] = BNReLU?(A)[M,K] @ W, bf16 MFMA ----------------
__global__ __launch_bounds__(256) void k_gemm_mfma(const float* __restrict__ A,
                                                    const unsigned short* __restrict__ Wt,
                                                    unsigned short* __restrict__ C,
                                                    const float* __restrict__ bnst,
                                                    const float* __restrict__ bng,
                                                    const float* __restrict__ bnbe,
                                                    int KT) {
    const int K = KT * 32;
    __shared__ __align__(16) unsigned short Asub[64 * 128];
    __shared__ float albe[256];
    int tid = threadIdx.x;
    int m0 = blockIdx.x * 64;
    if (bnst) {
        if (tid < 128) {
            float mean = bnst[tid] * (1.f / NN);
            float var = fmaf(-mean, mean, bnst[128 + tid] * (1.f / NN));
            float alpha = bng[tid] * rsqrtf(var + 1e-5f);
            albe[tid] = alpha;
            albe[128 + tid] = fmaf(-mean, alpha, bnbe[tid]);
        }
        __syncthreads();
    }
    const int kg8 = K >> 3;                       // 8-elem groups per row
    for (int i = tid; i < 64 * kg8; i += 256) {
        int r = i / kg8, kg = i - r * kg8;
        int m = m0 + r;
        short8 v8 = (short8){0, 0, 0, 0, 0, 0, 0, 0};
        if (m < NN) {
            f32x4 a0 = *(const f32x4*)(A + m * K + kg * 8);
            f32x4 a1 = *(const f32x4*)(A + m * K + kg * 8 + 4);
            if (bnst) {
#pragma unroll
                for (int e = 0; e < 4; ++e) {
                    int c = kg * 8 + e;
                    v8[e] = (short)f2bf(fmaxf(0.f, fmaf(a0[e], albe[c], albe[128 + c])));
                }
#pragma unroll
                for (int e = 0; e < 4; ++e) {
                    int c = kg * 8 + 4 + e;
                    v8[4 + e] = (short)f2bf(fmaxf(0.f, fmaf(a1[e], albe[c], albe[128 + c])));
                }
            } else {
#pragma unroll
                for (int e = 0; e < 4; ++e) v8[e] = (short)f2bf(a0[e]);
#pragma unroll
                for (int e = 0; e < 4; ++e) v8[4 + e] = (short)f2bf(a1[e]);
            }
        }
        *(short8*)(&Asub[r * K + kg * 8]) = v8;
    }
    __syncthreads();

    int lane = tid & 63, wv = tid >> 6;
    int q = lane >> 4, n = lane & 15;
    short8 afr[4];
#pragma unroll
    for (int kt = 0; kt < 4; ++kt)
        if (kt < KT) afr[kt] = *(const short8*)(&Asub[(16 * wv + n) * K + kt * 32 + q * 8]);

    for (int nt = 0; nt < 8; ++nt) {
        int wrow = nt * 16 + n;
        f32x4 acc = (f32x4){0.f, 0.f, 0.f, 0.f};
#pragma unroll
        for (int kt = 0; kt < 4; ++kt) {
            if (kt < KT) {
                short8 bfr = *(const short8*)(Wt + wrow * K + kt * 32 + q * 8);
                acc = __builtin_amdgcn_mfma_f32_16x16x32_bf16(afr[kt], bfr, acc, 0, 0, 0);
            }
        }
#pragma unroll
        for (int r = 0; r < 4; ++r) {
            int m = m0 + 16 * wv + 4 * q + r;
            if (m < NN) C[m * 128 + wrow] = f2bf(acc[r]);
        }
    }
}

// ---------------- CSR gather over bf16 h, 8 edge-groups per node, no atomics ----------------
__global__ __launch_bounds__(256) void k_gather(const unsigned short* __restrict__ h,
                                                 const int2* __restrict__ csw,
                                                 const int* __restrict__ off,
                                                 const float* __restrict__ bias,
                                                 float* __restrict__ agg) {
    int tid = threadIdx.x;
    int node = blockIdx.x;
    int g = tid >> 5;                  // edge group 0..7
    int q32 = tid & 31;
    f32x4 acc = (f32x4){0.f, 0.f, 0.f, 0.f};
    int beg = off[node], end = off[node + 1];

    int i = beg + g;
    int2 sw = (i < end) ? csw[i] : make_int2(0, 0);   // w=0 -> no-op contribution
    while (i < end) {
        int inext = i + 8;
        int2 swn = (inext < end) ? csw[inext] : make_int2(0, 0);
        float w = __int_as_float(sw.y);
        short4v hv = *(const short4v*)(h + sw.x * 128 + q32 * 4);
        f32x4 v = bf4_to_f32(hv);
        acc[0] = fmaf(v[0], w, acc[0]);
        acc[1] = fmaf(v[1], w, acc[1]);
        acc[2] = fmaf(v[2], w, acc[2]);
        acc[3] = fmaf(v[3], w, acc[3]);
        sw = swn;
        i = inext;
    }

    // combine the 8 groups
    __shared__ f32x4 part[256];
    part[tid] = acc;
    __syncthreads();
    if (g == 0) {
        f32x4 s = part[q32];
#pragma unroll
        for (int gg = 1; gg < 8; ++gg) s += part[gg * 32 + q32];
        const f32x4 bv = *(const f32x4*)(bias + q32 * 4);
        s += bv;
        *(f32x4*)(agg + node * 128 + q32 * 4) = s;
    }
}

// ---------------- per-feature sum / sumsq ----------------
__global__ __launch_bounds__(256) void k_bn_stats(const float* __restrict__ x,
                                                   float* __restrict__ stats) {
    int c = threadIdx.x & 127;
    int half = threadIdx.x >> 7;
    float s = 0.f, q = 0.f;
    for (int r = blockIdx.x * 2 + half; r < NN; r += gridDim.x * 2) {
        float v = x[r * HH + c];
        s += v;
        q = fmaf(v, v, q);
    }
    __shared__ float ls[256], lq[256];
    ls[threadIdx.x] = s;
    lq[threadIdx.x] = q;
    __syncthreads();
    if (half == 0) {
        atomicAdd(&stats[c], s + ls[128 + c]);
        atomicAdd(&stats[128 + c], q + lq[128 + c]);
    }
}

// ---------------- X_bf16[m][f][gate] = bf16(BNReLU(agg))[m,k] @ W_bf[gr,k]^T + bsum ----------------
__global__ __launch_bounds__(256) void k_mm512p(const float* __restrict__ A,
                                                 const float* __restrict__ bnst,
                                                 const float* __restrict__ bng,
                                                 const float* __restrict__ bnbe,
                                                 const unsigned short* __restrict__ Wfp,
                                                 const unsigned short* __restrict__ Wbp,
                                                 const float* __restrict__ bsf,
                                                 const float* __restrict__ bsb,
                                                 unsigned short* __restrict__ Xf,
                                                 unsigned short* __restrict__ Xb) {
    const int dir = blockIdx.y;
    const unsigned short* __restrict__ W = dir ? Wbp : Wfp;
    const float* __restrict__ bs = dir ? bsb : bsf;
    unsigned short* __restrict__ X = dir ? Xb : Xf;

    __shared__ __align__(16) unsigned short Asub[64 * 128];   // 16 KB
    __shared__ float albe[256];
    int tid = threadIdx.x;
    int m0 = blockIdx.x * 64;
    if (tid < 128) {
        float mean = bnst[tid] * (1.f / NN);
        float var = fmaf(-mean, mean, bnst[128 + tid] * (1.f / NN));
        float alpha = bng[tid] * rsqrtf(var + 1e-5f);
        albe[tid] = alpha;
        albe[128 + tid] = fmaf(-mean, alpha, bnbe[tid]);
    }
    __syncthreads();
    for (int i = tid; i < 1024; i += 256) {     // 64 rows x 16 (8-elem groups)
        int r = i >> 4, kg = i & 15;
        int m = m0 + r;
        short8 v8 = (short8){0, 0, 0, 0, 0, 0, 0, 0};
        if (m < NN) {
            f32x4 a0 = *(const f32x4*)(A + m * 128 + kg * 8);
            f32x4 a1 = *(const f32x4*)(A + m * 128 + kg * 8 + 4);
#pragma unroll
            for (int e = 0; e < 4; ++e) {
                int c = kg * 8 + e;
                v8[e] = (short)f2bf(fmaxf(0.f, fmaf(a0[e], albe[c], albe[128 + c])));
            }
#pragma unroll
            for (int e = 0; e < 4; ++e) {
                int c = kg * 8 + 4 + e;
                v8[4 + e] = (short)f2bf(fmaxf(0.f, fmaf(a1[e], albe[c], albe[128 + c])));
            }
        }
        *(short8*)(&Asub[r * 128 + kg * 8]) = v8;
    }
    __syncthreads();

    int lane = tid & 63, wv = tid >> 6;
    int q = lane >> 4, n = lane & 15;
    short8 afr[4];
#pragma unroll
    for (int kt = 0; kt < 4; ++kt)
        afr[kt] = *(const short8*)(&Asub[(16 * wv + n) * 128 + kt * 32 + q * 8]);

    for (int nt = 0; nt < 32; ++nt) {
        int gr = nt * 16 + n;
        short8 bfr[4];
#pragma unroll
        for (int kt = 0; kt < 4; ++kt)
            bfr[kt] = *(const short8*)(W + gr * 128 + kt * 32 + q * 8);
        f32x4 acc = (f32x4){0.f, 0.f, 0.f, 0.f};
#pragma unroll
        for (int kt = 0; kt < 4; ++kt)
            acc = __builtin_amdgcn_mfma_f32_16x16x32_bf16(afr[kt], bfr[kt], acc, 0, 0, 0);
        float b = bs[gr];
        int fg4 = (gr & 127) * 4 + (gr >> 7);
#pragma unroll
        for (int r = 0; r < 4; ++r) {
            int m = m0 + 16 * wv + 4 * q + r;
            if (m < NN) X[m * 512 + fg4] = f2bf(acc[r] + b);
        }
    }
}

// ---------------- segmented bidirectional LSTM scan (WARM=24, SEG=125, bf16 X) ----------------
__global__ __launch_bounds__(512, 1) void k_lstm(const unsigned short* __restrict__ xpf,
                                                  const unsigned short* __restrict__ xpb,
                                                  const float* __restrict__ whf,
                                                  const float* __restrict__ whb,
                                                  float* __restrict__ hf,
                                                  float* __restrict__ hb) {
    const int seg = blockIdx.x;
    const int dir = blockIdx.y;
    const unsigned short* __restrict__ xp = dir ? xpb : xpf;
    const float* __restrict__ Whh = dir ? whb : whf;
    float* __restrict__ hsp = dir ? hb : hf;
    const int j = threadIdx.x;
    const int lane = j & 63;
    const int w = j >> 6;
    const int g16 = lane >> 4;
    const int m = lane & 15;
    const int r2 = m & 3;
    const int f1 = 16 * w + 4 * g16 + r2;
    const bool writer = (m < 4);

    short8 af[4][4];
#pragma unroll
    for (int gt = 0; gt < 4; ++gt) {
#pragma unroll
        for (int kt = 0; kt < 4; ++kt) {
            const float* wp = Whh + (128 * gt + 16 * w + m) * 128 + 32 * kt + 8 * g16;
            float4 q0 = *(const float4*)wp;
            float4 q1 = *(const float4*)(wp + 4);
            short8 a;
            a[0] = (short)f2bf(q0.x); a[1] = (short)f2bf(q0.y);
            a[2] = (short)f2bf(q0.z); a[3] = (short)f2bf(q0.w);
            a[4] = (short)f2bf(q1.x); a[5] = (short)f2bf(q1.y);
            a[6] = (short)f2bf(q1.z); a[7] = (short)f2bf(q1.w);
            af[gt][kt] = a;
        }
    }

    __shared__ __align__(16) short h_bf[2][128];
    if (j < 128) h_bf[0][j] = 0;
    float c = 0.f;
    __syncthreads();

    // segment geometry (warm in {0,24}, QLEN=80: all even => loops stay 2x-unrolled)
    int warm, tfirst, tout;
    if (dir == 0) {
        int pre = seg * QLEN;
        warm = (pre < WARM) ? pre : WARM;
        tfirst = pre - warm;
        tout = pre;
    } else {
        int post = NN - (seg + 1) * QLEN;
        warm = (post < WARM) ? post : WARM;
        tfirst = (seg + 1) * QLEN - 1 + warm;
        tout = (seg + 1) * QLEN - 1;
    }

    const int xinc = dir ? -G4 : G4;               // ushorts per step
    const int hinc = dir ? -HH : HH;
    const unsigned short* xptr = xp + (size_t)tfirst * G4 + f1 * 4;
    float* hptr = hsp + tout * HH + f1;

    f32x4 xE = bf4_to_f32(*(const short4v*)xptr); xptr += xinc;
    f32x4 xO = bf4_to_f32(*(const short4v*)xptr); xptr += xinc;

#define LSTM_STEP(BUFR, BUFW, XV, WR)                                                    \
    {                                                                                    \
        const short8* hb8 = (const short8*)h_bf[BUFR];                                   \
        short8 bf0 = hb8[g16], bf1 = hb8[4 + g16], bf2 = hb8[8 + g16], bf3 = hb8[12 + g16]; \
        f32x4 acc[4];                                                                    \
        _Pragma("unroll")                                                                \
        for (int gt = 0; gt < 4; ++gt) acc[gt] = (f32x4){0.f, 0.f, 0.f, 0.f};            \
        _Pragma("unroll")                                                                \
        for (int gt = 0; gt < 4; ++gt)                                                   \
            acc[gt] = __builtin_amdgcn_mfma_f32_16x16x32_bf16(af[gt][0], bf0, acc[gt], 0, 0, 0); \
        _Pragma("unroll")                                                                \
        for (int gt = 0; gt < 4; ++gt)                                                   \
            acc[gt] = __builtin_amdgcn_mfma_f32_16x16x32_bf16(af[gt][1], bf1, acc[gt], 0, 0, 0); \
        _Pragma("unroll")                                                                \
        for (int gt = 0; gt < 4; ++gt)                                                   \
            acc[gt] = __builtin_amdgcn_mfma_f32_16x16x32_bf16(af[gt][2], bf2, acc[gt], 0, 0, 0); \
        _Pragma("unroll")                                                                \
        for (int gt = 0; gt < 4; ++gt)                                                   \
            acc[gt] = __builtin_amdgcn_mfma_f32_16x16x32_bf16(af[gt][3], bf3, acc[gt], 0, 0, 0); \
        float gv[4];                                                                     \
        _Pragma("unroll")                                                                \
        for (int r = 0; r < 4; ++r) {                                                    \
            float lo = (r2 & 1) ? acc[r][1] : acc[r][0];                                 \
            float hi = (r2 & 1) ? acc[r][3] : acc[r][2];                                 \
            gv[r] = (r2 & 2) ? hi : lo;                                                  \
        }                                                                                \
        float ig = sigm(gv[0] + (XV)[0]);                                                \
        float fg = sigm(gv[1] + (XV)[1]);                                                \
        float cg = tanh_fast(gv[2] + (XV)[2]);                                           \
        float og = sigm(gv[3] + (XV)[3]);                                                \
        c = fmaf(fg, c, ig * cg);                                                        \
        float h = og * tanh_fast(c);                                                     \
        if (writer) {                                                                    \
            if (WR) *hptr = h;                                                           \
            h_bf[BUFW][f1] = (short)f2bf(h);                                             \
        }                                                                                \
        if (WR) hptr += hinc;                                                            \
    }

    // ---- warmup (no output writes) ----
    for (int s = 0; s < warm; s += 2) {
        f32x4 xE2 = bf4_to_f32(*(const short4v*)xptr); xptr += xinc;
        LSTM_STEP(0, 1, xE, 0)
        asm volatile("s_waitcnt lgkmcnt(0)\n\ts_barrier" ::: "memory");

        f32x4 xO2 = bf4_to_f32(*(const short4v*)xptr); xptr += xinc;
        LSTM_STEP(1, 0, xO, 0)
        asm volatile("s_waitcnt lgkmcnt(0)\n\ts_barrier" ::: "memory");

        xE = xE2;
        xO = xO2;
    }
    // ---- main (writes enabled) ----
    for (int s = 0; s < QLEN; s += 2) {
        f32x4 xE2 = bf4_to_f32(*(const short4v*)xptr); xptr += xinc;
        LSTM_STEP(0, 1, xE, 1)
        asm volatile("s_waitcnt lgkmcnt(0)\n\ts_barrier" ::: "memory");

        f32x4 xO2 = bf4_to_f32(*(const short4v*)xptr); xptr += xinc;
        LSTM_STEP(1, 0, xO, 1)
        asm volatile("s_waitcnt lgkmcnt(0)\n\ts_barrier" ::: "memory");

        xE = xE2;
        xO = xO2;
    }
#undef LSTM_STEP
}

// ---------------- out = [hf|hb] @ Wo + bo ----------------
__global__ void k_out(const float* __restrict__ hf, const float* __restrict__ hb,
                      const float* __restrict__ Wo, const float* __restrict__ bo,
                      float* __restrict__ out) {
    int idx = blockIdx.x * 256 + threadIdx.x;
    if (idx >= NN * 12) return;
    int n = idx / 12;
    int p = idx - n * 12;
    float acc = bo[p];
    const float4* hfr = (const float4*)(hf + n * 128);
    const float4* hbr = (const float4*)(hb + n * 128);
#pragma unroll 4
    for (int k4 = 0; k4 < 32; ++k4) {
        float4 v = hfr[k4];
        acc = fmaf(v.x, Wo[(4 * k4 + 0) * 12 + p], acc);
        acc = fmaf(v.y, Wo[(4 * k4 + 1) * 12 + p], acc);
        acc = fmaf(v.z, Wo[(4 * k4 + 2) * 12 + p], acc);
        acc = fmaf(v.w, Wo[(4 * k4 + 3) * 12 + p], acc);
    }
#pragma unroll 4
    for (int k4 = 0; k4 < 32; ++k4) {
        float4 v = hbr[k4];
        acc = fmaf(v.x, Wo[(128 + 4 * k4 + 0) * 12 + p], acc);
        acc = fmaf(v.y, Wo[(128 + 4 * k4 + 1) * 12 + p], acc);
        acc = fmaf(v.z, Wo[(128 + 4 * k4 + 2) * 12 + p], acc);
        acc = fmaf(v.w, Wo[(128 + 4 * k4 + 3) * 12 + p], acc);
    }
    out[idx] = acc;
}

extern "C" void kernel_launch(void* const* d_in, const int* in_sizes, int n_in,
                              void* d_out, int out_size, void* d_ws, size_t ws_size,
                              hipStream_t stream) {
    const float* x    = (const float*)d_in[0];
    const int*   ei   = (const int*)d_in[1];
    const float* ew   = (const float*)d_in[2];
    const float* W1   = (const float*)d_in[3];
    const float* b1   = (const float*)d_in[4];
    const float* g1   = (const float*)d_in[5];
    const float* be1  = (const float*)d_in[6];
    const float* W2   = (const float*)d_in[7];
    const float* b2   = (const float*)d_in[8];
    const float* g2   = (const float*)d_in[9];
    const float* be2  = (const float*)d_in[10];
    const float* Wihf = (const float*)d_in[11];
    const float* Whhf = (const float*)d_in[12];
    const float* bihf = (const float*)d_in[13];
    const float* bhhf = (const float*)d_in[14];
    const float* Wihb = (const float*)d_in[15];
    const float* Whhb = (const float*)d_in[16];
    const float* bihb = (const float*)d_in[17];
    const float* bhhb = (const float*)d_in[18];
    const float* Wo   = (const float*)d_in[21];
    const float* bo   = (const float*)d_in[22];
    float* out = (float*)d_out;
    float* ws  = (float*)d_ws;

    // ---- buffers (float offsets; bf16 buffers reinterpret the same regions) ----
    unsigned short* bufA = (unsigned short*)ws;        // 1.28M ushort (GEMM out, bf16)
    float* bufB  = ws + 1280000;       // 1,280,000 fp32 (agg)
    float* stats = ws + 3840000;       // 512
    unsigned short* Xf = (unsigned short*)(ws + 3840512);   // 5.12M ushort
    unsigned short* Xb = (unsigned short*)(ws + 8960512);   // 5.12M ushort
    float* hfp   = ws + 14080512;      // 1,280,000
    float* hbp   = ws + 15360512;      // 1,280,000

    // ---- overlay region inside hfp/hbp (all consumed before k_lstm writes them) ----
    // Disjointness audit (float offsets):
    //   wfbf [14,720,512 - 14,753,280)  wbbf [14,753,280 - 14,786,048)
    //   bsumf[14,786,048 - 14,786,560)  bsumb[14,786,560 - 14,787,072)
    //   icnt [14,787,072 - 14,797,072)  ioff [14,797,072 - 14,807,073)
    //   csw  [14,807,074 - 15,447,074)
    //   w1t  [15,447,076 - 15,451,172)  w2t [15,451,172 - 15,459,364)
    unsigned short* wfbf = (unsigned short*)(ws + 14720512);
    unsigned short* wbbf = (unsigned short*)(ws + 14753280);
    float* bsumf = ws + 14786048;
    float* bsumb = ws + 14786560;
    int* icnt = (int*)(ws + 14787072);
    int* ioff = icnt + 10000;
    int2* csw = (int2*)(ws + 14807074);
    unsigned short* w1t  = (unsigned short*)(ws + 15447076);
    unsigned short* w2t  = (unsigned short*)(ws + 15451172);

    const int gEdge = (EE + 255) / 256;

    // ---- CSR build + weight converts ----
    k_zero<<<(NN + 255) / 256, 256, 0, stream>>>(stats, icnt);
    k_hist<<<gEdge, 256, 0, stream>>>(ei, icnt, Wihf, Wihb, bihf, bhhf, bihb, bhhb,
                                      W1, W2, wfbf, wbbf, w1t, w2t, bsumf, bsumb);
    k_scan<<<1, 1024, 0, stream>>>(icnt, ioff);
    k_fill<<<gEdge, 256, 0, stream>>>(ei, ew, ioff, icnt, csw);

    // ---- GCN layer 1 (bf16 MFMA, bf16 out) ----
    k_gemm_mfma<<<157, 256, 0, stream>>>(x, w1t, bufA,
                                         (const float*)0, (const float*)0, (const float*)0, 2);
    k_gather<<<NN, 256, 0, stream>>>(bufA, csw, ioff, b1, bufB);
    k_bn_stats<<<250, 256, 0, stream>>>(bufB, stats);

    // ---- GCN layer 2 (BN1+ReLU fused into bf16 staging, MFMA, bf16 out) ----
    k_gemm_mfma<<<157, 256, 0, stream>>>(bufB, w2t, bufA, stats, g1, be1, 4);
    k_gather<<<NN, 256, 0, stream>>>(bufA, csw, ioff, b2, bufB);
    k_bn_stats<<<250, 256, 0, stream>>>(bufB, stats + 256);

    // ---- LSTM input projections (BN2+ReLU+bf16 fused; X stored bf16) ----
    dim3 gmm(157, 2);
    k_mm512p<<<gmm, 256, 0, stream>>>(bufB, stats + 256, g2, be2,
                                      wfbf, wbbf, bsumf, bsumb, Xf, Xb);

    // ---- segmented bidirectional scan: SEG x 2 dirs, 104 steps max ----
    dim3 gl(SEG, 2);
    k_lstm<<<gl, 512, 0, stream>>>(Xf, Xb, Whhf, Whhb, hfp, hbp);

    // ---- attention is identity; final matmul ----
    k_out<<<(NN * 12 + 255) / 256, 256, 0, stream>>>(hfp, hbp, Wo, bo, out);
}